// Round 10
// baseline (124.168 us; speedup 1.0000x reference)
//
#include <hip/hip_runtime.h>
#include <hip/hip_bf16.h>
#include <math.h>

#define H 128
#define TT 64
#define TWO_H 256
#define NGX 128
#define NACC 128
#define NTOT 512

typedef short short8 __attribute__((ext_vector_type(8)));
typedef __bf16 bf16x8_t __attribute__((ext_vector_type(8)));
typedef float f32x4 __attribute__((ext_vector_type(4)));
typedef unsigned int uint;

__device__ inline unsigned short bf_rne(float f) {
    __hip_bfloat16 b = __float2bfloat16(f);
    return __builtin_bit_cast(unsigned short, b);
}
__device__ inline void split_rne(float f, unsigned short& hi, unsigned short& lo) {
    __hip_bfloat16 h1 = __float2bfloat16(f);
    float fh = __bfloat162float(h1);
    hi = __builtin_bit_cast(unsigned short, h1);
    lo = bf_rne(f - fh);
}
__device__ inline f32x4 mfma_bf16(short8 a, short8 b, f32x4 c) {
    return __builtin_amdgcn_mfma_f32_16x16x32_bf16(
        __builtin_bit_cast(bf16x8_t, a), __builtin_bit_cast(bf16x8_t, b), c, 0, 0, 0);
}
__device__ inline float sigf(float x) { return 1.f / (1.f + __expf(-x)); }

// ---------- fallback (only if workspace too small for histogram path) ----------
__global__ void k_edges_fb(const float* __restrict__ nodes, const int* __restrict__ src,
                           const int* __restrict__ rel, const int* __restrict__ dst,
                           float* __restrict__ Sg, float* __restrict__ cntg, int E, int epb) {
    __shared__ float Sl[8 * 512];
    __shared__ float cnt[8];
    int t = threadIdx.x;
    for (int i = t; i < 8 * 512; i += 256) Sl[i] = 0.f;
    if (t < 8) cnt[t] = 0.f;
    __syncthreads();
    int e0 = blockIdx.x * epb, e1 = min(E, e0 + epb);
    int tS = ((t >> 7) << 8) + (t & 127);
    for (int e = e0; e < e1; ++e) {
        int r = rel[e];
        float vs = nodes[(size_t)src[e] * 256 + t];
        float vd = nodes[(size_t)dst[e] * 256 + t];
        Sl[r * 512 + tS] += vs;
        Sl[r * 512 + tS + 128] += vd;
        if (t == 0) cnt[r] += 1.f;
    }
    __syncthreads();
    for (int i = t; i < 8 * 512; i += 256) atomicAdd(&Sg[i], Sl[i]);
    if (t < 8) atomicAdd(&cntg[t], cnt[t]);
}

// ============ single fused kernel: GRU | combine | gx+count | accum | burn ============
__launch_bounds__(256, 1)
__global__ void k_fused(const float* __restrict__ nodes, const int* __restrict__ src,
                        const int* __restrict__ rel, const int* __restrict__ dst,
                        const float* __restrict__ x, const float* __restrict__ Wih,
                        const float* __restrict__ bih, uint* __restrict__ csd,
                        float* __restrict__ Sg, float* __restrict__ cntg,
                        const float* __restrict__ relW, const float* __restrict__ relb,
                        float* __restrict__ gs, int* __restrict__ flags, float invE,
                        float* __restrict__ gxT2, const float* __restrict__ Whh,
                        const float* __restrict__ bhh, const float* __restrict__ W1,
                        const float* __restrict__ b1, const float* __restrict__ lng,
                        const float* __restrict__ lnb, const float* __restrict__ W2,
                        const float* __restrict__ b2v, float* __restrict__ out,
                        int N, int E, int nch, int naccum, int hist, int nreal) {
    int t = threadIdx.x;
    int bid = blockIdx.x;

    if (bid >= nreal) {
        // ============ burn: keep CUs busy (DVFS) until GRU signals done ============
        __shared__ int sdone;
        if (t == 0) sdone = 0;
        __syncthreads();
        float xx = (float)(t + 1) * 1e-8f;
        while (true) {
            if (t == 0) sdone = (atomicAdd(&flags[4], 0) != 0) ? 1 : 0;
            __syncthreads();
            if (sdone) break;
            // low-issue dependent FMA chain: keeps the CU "busy" without
            // stealing many issue slots from co-resident real work
#pragma unroll 8
            for (int i = 0; i < 256; ++i) xx = __builtin_fmaf(xx, 1.0000001f, 1e-9f);
            __syncthreads();
        }
        asm volatile("" ::"v"(xx));  // keep the chain alive (no DCE)
        return;
    }

    if (bid >= 9 && bid < 9 + NGX) {
        // ================= gx block (+ count slice when hist) =================
        int idx = bid - 9;
        if (hist) {
            int per = (E + NGX - 1) / NGX;
            int e0 = idx * per, e1 = min(E, e0 + per);
            for (int e = e0 + t; e < e1; e += 256) {
                int r = rel[e];
                atomicAdd(&csd[(size_t)src[e] * 8 + r], 1u);
                atomicAdd(&csd[(size_t)dst[e] * 8 + r], 65536u);
            }
            __syncthreads();
            if (t == 0) {
                __threadfence();
                atomicAdd(&flags[3], 1);
            }
        }
        // gx: gxT2[tt][j][b][4] = {r,z,n,pad}; bhh folded for r,z
        __shared__ float xs[H];
        int tt = idx >> 1, bb = idx & 1;
        if (t < H) xs[t] = x[(bb * TT + tt) * H + t];
        __syncthreads();
        for (int o = t; o < 384; o += 256) {
            const float4* wp = (const float4*)(Wih + o * H);
            float acc = 0.f;
#pragma unroll
            for (int i = 0; i < 32; ++i) {
                float4 w = wp[i];
                acc += w.x * xs[4 * i] + w.y * xs[4 * i + 1] + w.z * xs[4 * i + 2] +
                       w.w * xs[4 * i + 3];
            }
            float bias = bih[o] + (o < TWO_H ? bhh[o] : 0.f);  // bhh_n not foldable
            int g = o >> 7, j = o & 127;
            gxT2[((size_t)(tt * 128 + j) * 2 + bb) * 4 + g] = acc + bias;
        }
        __syncthreads();
        if (t == 0) {
            __threadfence();
            atomicAdd(&flags[2], 1);
        }
        return;
    }

    if (bid >= 9 + NGX) {
        // ================= accum: stream nodes once, weighted by counts =================
        int ai = bid - 9 - NGX;
        if (t == 0) {
            while (atomicAdd(&flags[3], 0) < NGX) __builtin_amdgcn_s_sleep(8);
            __threadfence();
        }
        __syncthreads();
        int n0 = ai * nch, n1 = min(N, n0 + nch);
        float sA[8] = {0, 0, 0, 0, 0, 0, 0, 0};
        float sB[8] = {0, 0, 0, 0, 0, 0, 0, 0};
        float caR[8] = {0, 0, 0, 0, 0, 0, 0, 0};
        int n = n0;
        for (; n + 4 <= n1; n += 4) {
            float v0 = nodes[(size_t)(n + 0) * 256 + t];
            float v1 = nodes[(size_t)(n + 1) * 256 + t];
            float v2 = nodes[(size_t)(n + 2) * 256 + t];
            float v3 = nodes[(size_t)(n + 3) * 256 + t];
            uint4 a0 = *(const uint4*)(csd + (size_t)(n + 0) * 8);
            uint4 a1 = *(const uint4*)(csd + (size_t)(n + 0) * 8 + 4);
            uint4 b0 = *(const uint4*)(csd + (size_t)(n + 1) * 8);
            uint4 b1u = *(const uint4*)(csd + (size_t)(n + 1) * 8 + 4);
            uint4 c0 = *(const uint4*)(csd + (size_t)(n + 2) * 8);
            uint4 c1 = *(const uint4*)(csd + (size_t)(n + 2) * 8 + 4);
            uint4 d0 = *(const uint4*)(csd + (size_t)(n + 3) * 8);
            uint4 d1 = *(const uint4*)(csd + (size_t)(n + 3) * 8 + 4);
            uint ca[8] = {a0.x, a0.y, a0.z, a0.w, a1.x, a1.y, a1.z, a1.w};
            uint cb[8] = {b0.x, b0.y, b0.z, b0.w, b1u.x, b1u.y, b1u.z, b1u.w};
            uint cc[8] = {c0.x, c0.y, c0.z, c0.w, c1.x, c1.y, c1.z, c1.w};
            uint cd2[8] = {d0.x, d0.y, d0.z, d0.w, d1.x, d1.y, d1.z, d1.w};
#pragma unroll
            for (int r = 0; r < 8; ++r) {
                float fs0 = (float)(ca[r] & 0xffffu), fd0 = (float)(ca[r] >> 16);
                float fs1 = (float)(cb[r] & 0xffffu), fd1 = (float)(cb[r] >> 16);
                float fs2 = (float)(cc[r] & 0xffffu), fd2 = (float)(cc[r] >> 16);
                float fs3 = (float)(cd2[r] & 0xffffu), fd3 = (float)(cd2[r] >> 16);
                sA[r] += fs0 * v0 + fs1 * v1 + fs2 * v2 + fs3 * v3;
                sB[r] += fd0 * v0 + fd1 * v1 + fd2 * v2 + fd3 * v3;
                caR[r] += fs0 + fs1 + fs2 + fs3;
            }
        }
        for (; n < n1; ++n) {
            float v = nodes[(size_t)n * 256 + t];
            const uint* cp = csd + (size_t)n * 8;
            uint4 c0 = *(const uint4*)cp;
            uint4 c1 = *(const uint4*)(cp + 4);
            uint cc[8] = {c0.x, c0.y, c0.z, c0.w, c1.x, c1.y, c1.z, c1.w};
#pragma unroll
            for (int r = 0; r < 8; ++r) {
                float fs = (float)(cc[r] & 0xffffu);
                float fd = (float)(cc[r] >> 16);
                sA[r] += fs * v;
                sB[r] += fd * v;
                caR[r] += fs;
            }
        }
        int b = t >> 7, h = t & 127;
#pragma unroll
        for (int r = 0; r < 8; ++r) {
            atomicAdd(&Sg[r * 512 + b * 256 + h], sA[r]);
            atomicAdd(&Sg[r * 512 + b * 256 + 128 + h], sB[r]);
        }
        if (t == 0) {
#pragma unroll
            for (int r = 0; r < 8; ++r) atomicAdd(&cntg[r], caR[r]);
        }
        __syncthreads();
        if (t == 0) {
            __threadfence();
            atomicAdd(&flags[0], 1);
        }
        return;
    }

    if (bid >= 1) {
        // ================= combine r: gs += (S_r @ W_r + cnt_r*b_r)/E =================
        int r = bid - 1;
        __shared__ float Sc[512];
        if (t == 0) {
            while (atomicAdd(&flags[0], 0) < naccum) __builtin_amdgcn_s_sleep(8);
        }
        __syncthreads();
        for (int i = t; i < 512; i += 256) Sc[i] = atomicAdd(&Sg[r * 512 + i], 0.f);
        __syncthreads();
        int b = t >> 7, h = t & 127;
        const float* Wr = relW + (size_t)r * TWO_H * H;
        float acc = 0.f;
#pragma unroll 8
        for (int c = 0; c < TWO_H; ++c) acc += Sc[b * 256 + c] * Wr[c * H + h];
        acc += atomicAdd(&cntg[r], 0.f) * relb[r * H + h];
        atomicAdd(&gs[t], acc * invE);
        __syncthreads();
        if (t == 0) {
            __threadfence();
            atomicAdd(&flags[1], 1);
        }
        return;
    }

    // ================= block 0: GRU, 4 waves, LDS-staged gx =================
    __shared__ __align__(16) unsigned short h2[2][5][144];
    __shared__ __align__(16) float gxs[2][8][256][4];  // 2 x 32KB staged gx chunks
    __shared__ float hfl[256];
    __shared__ float gl2[2][H];
    __shared__ float yl[2][TWO_H];
    __shared__ float red[16];

    int w = t >> 6, l = t & 63;

    for (int i = t; i < 2 * 5 * 144; i += 256) ((unsigned short*)h2)[i] = 0;

    // B fragments: wave w owns j in [32w,32w+32): tiles ti=(g=ti>>1, jh=ti&1)
    short8 Bf[6][4];
#pragma unroll
    for (int ti = 0; ti < 6; ++ti) {
        int row = ((ti >> 1) * 8 + 2 * w + (ti & 1)) * 16 + (l & 15);
#pragma unroll
        for (int kt = 0; kt < 4; ++kt) {
            const float4* wp = (const float4*)(Whh + row * H + kt * 32 + (l >> 4) * 8);
            float4 w0 = wp[0], w1 = wp[1];
            float ww[8] = {w0.x, w0.y, w0.z, w0.w, w1.x, w1.y, w1.z, w1.w};
            short8 v8;
#pragma unroll
            for (int e = 0; e < 8; ++e) v8[e] = (short)bf_rne(ww[e]);
            Bf[ti][kt] = v8;
        }
    }

    int al = l & 15;
    int rr = al < 4 ? al : 4;  // A-row; rows >=4 read the zero row (broadcast)
    int kg = (l >> 4) * 8;

    // gate lanes: l<16; 4 units each: (b, jh), j = w*32 + jh*16 + l
    float hpv[2][2] = {{0.f, 0.f}, {0.f, 0.f}};  // [jh][b]
    float bhnv[2];
    int j0 = w * 32 + l;
    if (l < 16) {
        bhnv[0] = bhh[TWO_H + j0];
        bhnv[1] = bhh[TWO_H + j0 + 16];
    }

    // wait for all gx blocks, then stage chunk 0
    if (t == 0) {
        while (atomicAdd(&flags[2], 0) < NGX) __builtin_amdgcn_s_sleep(4);
        __threadfence();
    }
    __syncthreads();

    {
        float* lb = &gxs[0][0][0][0];
#pragma unroll
        for (int i = 0; i < 8; ++i) {
            __builtin_amdgcn_global_load_lds(
                (const __attribute__((address_space(1))) uint*)(gxT2 + w * 2048 + i * 256 + l * 4),
                (__attribute__((address_space(3))) uint*)(lb + w * 2048 + i * 256),
                16, 0, 0);
        }
    }
    __syncthreads();  // drains vmcnt(0): chunk 0 staged; h2 zeros visible

    __builtin_amdgcn_s_setprio(1);  // favor GRU waves over any co-resident burn block
    for (int c = 0; c < 8; ++c) {
        if (c < 7) {
            float* lb = &gxs[(c + 1) & 1][0][0][0];
            const float* sb = gxT2 + (size_t)(c + 1) * 8192;
#pragma unroll
            for (int i = 0; i < 8; ++i) {
                __builtin_amdgcn_global_load_lds(
                    (const __attribute__((address_space(1))) uint*)(sb + w * 2048 + i * 256 + l * 4),
                    (__attribute__((address_space(3))) uint*)(lb + w * 2048 + i * 256),
                    16, 0, 0);
            }
        }
#pragma unroll
        for (int i = 0; i < 8; ++i) {
            int p = i & 1, q = p ^ 1;

            short8 A[4];
#pragma unroll
            for (int kt = 0; kt < 4; ++kt)
                A[kt] = *(const short8*)&h2[p][rr][kt * 32 + kg];

            f32x4 acc[6];
#pragma unroll
            for (int ti = 0; ti < 6; ++ti) acc[ti] = (f32x4){0.f, 0.f, 0.f, 0.f};
#pragma unroll
            for (int kt = 0; kt < 4; ++kt) {
#pragma unroll
                for (int ti = 0; ti < 6; ++ti) acc[ti] = mfma_bf16(A[kt], Bf[ti][kt], acc[ti]);
            }

            if (l < 16) {
#pragma unroll
                for (int jh = 0; jh < 2; ++jh) {
#pragma unroll
                    for (int b = 0; b < 2; ++b) {
                        const float4 cg = *(const float4*)&gxs[c & 1][i][(j0 + jh * 16) * 2 + b][0];
                        float ghr = acc[0 * 2 + jh][b] + acc[0 * 2 + jh][2 + b];
                        float ghz = acc[1 * 2 + jh][b] + acc[1 * 2 + jh][2 + b];
                        float ghn = acc[2 * 2 + jh][b] + acc[2 * 2 + jh][2 + b];
                        float rg = sigf(cg.x + ghr);
                        float zg = sigf(cg.y + ghz);
                        float nn = cg.z + rg * (ghn + bhnv[jh]);
                        float th = 2.f * sigf(2.f * nn) - 1.f;
                        float hn2 = (1.f - zg) * th + zg * hpv[jh][b];
                        hpv[jh][b] = hn2;
                        unsigned short hh, ll;
                        split_rne(hn2, hh, ll);
                        int j = j0 + jh * 16;
                        h2[q][b][j] = hh;
                        h2[q][2 + b][j] = ll;
                    }
                }
            }
            __builtin_amdgcn_sched_barrier(0);
            if (i == 7) {
                asm volatile("s_waitcnt vmcnt(0) lgkmcnt(0)" ::: "memory");
            } else {
                asm volatile("s_waitcnt lgkmcnt(0)" ::: "memory");
            }
            __builtin_amdgcn_s_barrier();
            __builtin_amdgcn_sched_barrier(0);
        }
    }
    __builtin_amdgcn_s_setprio(0);

    // ---- tail: wait combine, then MLP + LN ----
    if (l < 16) {
#pragma unroll
        for (int jh = 0; jh < 2; ++jh)
#pragma unroll
            for (int b = 0; b < 2; ++b) hfl[b * 128 + j0 + jh * 16] = hpv[jh][b];
    }
    if (t == 0) {
        while (atomicAdd(&flags[1], 0) < 8) __builtin_amdgcn_s_sleep(8);
    }
    __syncthreads();
    gl2[t >> 7][t & 127] = atomicAdd(&gs[t], 0.f) + hfl[t];
    __syncthreads();

    float h1_0 = b1[t], h1_1 = b1[t];
    for (int i = 0; i < H; ++i) {
        float wv = W1[i * TWO_H + t];
        h1_0 += gl2[0][i] * wv;
        h1_1 += gl2[1][i] * wv;
    }
    float s10 = h1_0, s20 = h1_0 * h1_0, s11 = h1_1, s21 = h1_1 * h1_1;
#pragma unroll
    for (int off = 32; off; off >>= 1) {
        s10 += __shfl_xor(s10, off);
        s20 += __shfl_xor(s20, off);
        s11 += __shfl_xor(s11, off);
        s21 += __shfl_xor(s21, off);
    }
    if (l == 0) {
        red[w * 4 + 0] = s10; red[w * 4 + 1] = s20;
        red[w * 4 + 2] = s11; red[w * 4 + 3] = s21;
    }
    __syncthreads();
    {
        float S10 = red[0] + red[4] + red[8] + red[12];
        float S20 = red[1] + red[5] + red[9] + red[13];
        float S11 = red[2] + red[6] + red[10] + red[14];
        float S21 = red[3] + red[7] + red[11] + red[15];
        float mu0 = S10 / 256.f, mu1 = S11 / 256.f;
        float v0 = S20 / 256.f - mu0 * mu0, v1 = S21 / 256.f - mu1 * mu1;
        float is0 = rsqrtf(v0 + 1e-5f), is1 = rsqrtf(v1 + 1e-5f);
        float y0 = (h1_0 - mu0) * is0 * lng[t] + lnb[t];
        float y1 = (h1_1 - mu1) * is1 * lng[t] + lnb[t];
        yl[0][t] = fmaxf(y0, 0.f);
        yl[1][t] = fmaxf(y1, 0.f);
    }
    __syncthreads();
    if (t < H) {
        float a0 = b2v[t], a1 = b2v[t];
        for (int i = 0; i < TWO_H; ++i) {
            float wv = W2[i * H + t];
            a0 += yl[0][i] * wv;
            a1 += yl[1][i] * wv;
        }
        out[t] = a0;
        out[H + t] = a1;
    }
    __syncthreads();
    if (t == 0) {
        __threadfence();
        atomicAdd(&flags[4], 1);  // release burn blocks
    }
}

extern "C" void kernel_launch(void* const* d_in, const int* in_sizes, int n_in,
                              void* d_out, int out_size, void* d_ws, size_t ws_size,
                              hipStream_t stream) {
    const float* nodes = (const float*)d_in[0];
    const float* temporal = (const float*)d_in[1];
    const float* relW = (const float*)d_in[2];
    const float* relb = (const float*)d_in[3];
    const float* gru_Wih = (const float*)d_in[4];
    const float* gru_Whh = (const float*)d_in[5];
    const float* gru_bih = (const float*)d_in[6];
    const float* gru_bhh = (const float*)d_in[7];
    const float* mlp_W1 = (const float*)d_in[8];
    const float* mlp_b1 = (const float*)d_in[9];
    const float* ln_g = (const float*)d_in[10];
    const float* ln_b = (const float*)d_in[11];
    const float* mlp_W2 = (const float*)d_in[12];
    const float* mlp_b2 = (const float*)d_in[13];
    const int* src = (const int*)d_in[14];
    const int* rel = (const int*)d_in[15];
    const int* dst = (const int*)d_in[16];
    float* out = (float*)d_out;

    int E = in_sizes[14];
    int N = in_sizes[0] / 256;

    // ws layout (float units): gs | cntg | flags | Sg | csd | gxT2
    float* ws = (float*)d_ws;
    float* gs = ws;                     // 256
    float* cntg = ws + 256;             // 8
    int* flags = (int*)(ws + 264);      // 8
    float* Sg = ws + 272;               // 4096
    uint* csd = (uint*)(ws + 4368);     // 8*N (hist only)

    size_t need_hist = (size_t)(4368 + 8 * N + 65536) * 4;
    int hist = ws_size >= need_hist ? 1 : 0;

    float* gxT2 = hist ? (ws + 4368 + 8 * N) : (ws + 4368);
    size_t zbytes = hist ? (size_t)(4368 + 8 * N) * 4 : (size_t)4368 * 4;
    hipMemsetAsync(d_ws, 0, zbytes, stream);

    int naccum, nreal;
    if (hist) {
        naccum = NACC;
        nreal = 9 + NGX + NACC;
    } else {
        int epb = (E + 511) / 512;
        k_edges_fb<<<512, 256, 0, stream>>>(nodes, src, rel, dst, Sg, cntg, E, epb);
        naccum = 0;
        nreal = 9 + NGX;
    }
    int nch = (N + NACC - 1) / NACC;
    int nblk = NTOT;  // nreal worker blocks + (NTOT - nreal) burn blocks, all co-resident

    k_fused<<<nblk, 256, 0, stream>>>(nodes, src, rel, dst, temporal, gru_Wih, gru_bih,
                                      csd, Sg, cntg, relW, relb, gs, flags,
                                      1.f / (float)E, gxT2, gru_Whh, gru_bhh, mlp_W1,
                                      mlp_b1, ln_g, ln_b, mlp_W2, mlp_b2, out,
                                      N, E, nch, naccum, hist, nreal);
}

// Round 11
// 115.089 us; speedup vs baseline: 1.0789x; 1.0789x over previous
//
#include <hip/hip_runtime.h>
#include <hip/hip_bf16.h>
#include <math.h>

#define H 128
#define TT 64
#define TWO_H 256
#define NGX 128
#define NACC 128

typedef short short8 __attribute__((ext_vector_type(8)));
typedef __bf16 bf16x8_t __attribute__((ext_vector_type(8)));
typedef float f32x4 __attribute__((ext_vector_type(4)));
typedef unsigned int uint;

__device__ inline unsigned short bf_rne(float f) {
    __hip_bfloat16 b = __float2bfloat16(f);
    return __builtin_bit_cast(unsigned short, b);
}
__device__ inline void split_rne(float f, unsigned short& hi, unsigned short& lo) {
    __hip_bfloat16 h1 = __float2bfloat16(f);
    float fh = __bfloat162float(h1);
    hi = __builtin_bit_cast(unsigned short, h1);
    lo = bf_rne(f - fh);
}
__device__ inline f32x4 mfma_bf16(short8 a, short8 b, f32x4 c) {
    return __builtin_amdgcn_mfma_f32_16x16x32_bf16(
        __builtin_bit_cast(bf16x8_t, a), __builtin_bit_cast(bf16x8_t, b), c, 0, 0, 0);
}
__device__ inline float sigf(float x) { return 1.f / (1.f + __expf(-x)); }

// ---------- fallback (only if workspace too small for histogram path) ----------
__global__ void k_edges_fb(const float* __restrict__ nodes, const int* __restrict__ src,
                           const int* __restrict__ rel, const int* __restrict__ dst,
                           float* __restrict__ Sg, float* __restrict__ cntg, int E, int epb) {
    __shared__ float Sl[8 * 512];
    __shared__ float cnt[8];
    int t = threadIdx.x;
    for (int i = t; i < 8 * 512; i += 256) Sl[i] = 0.f;
    if (t < 8) cnt[t] = 0.f;
    __syncthreads();
    int e0 = blockIdx.x * epb, e1 = min(E, e0 + epb);
    int tS = ((t >> 7) << 8) + (t & 127);
    for (int e = e0; e < e1; ++e) {
        int r = rel[e];
        float vs = nodes[(size_t)src[e] * 256 + t];
        float vd = nodes[(size_t)dst[e] * 256 + t];
        Sl[r * 512 + tS] += vs;
        Sl[r * 512 + tS + 128] += vd;
        if (t == 0) cnt[r] += 1.f;
    }
    __syncthreads();
    for (int i = t; i < 8 * 512; i += 256) atomicAdd(&Sg[i], Sl[i]);
    if (t < 8) atomicAdd(&cntg[t], cnt[t]);
}

// ============ single fused kernel: GRU | combine | gx(+count) | accum ============
// flags: [0]=accum done, [1]=combine done, [2]=count done (per gx block),
//        [8+g]=gx chunk-group g done (16 blocks per group, g=0..7)
__launch_bounds__(256, 1)
__global__ void k_fused(const float* __restrict__ nodes, const int* __restrict__ src,
                        const int* __restrict__ rel, const int* __restrict__ dst,
                        const float* __restrict__ x, const float* __restrict__ Wih,
                        const float* __restrict__ bih, uint* __restrict__ csd,
                        float* __restrict__ Sg, float* __restrict__ cntg,
                        const float* __restrict__ relW, const float* __restrict__ relb,
                        float* __restrict__ gs, int* __restrict__ flags, float invE,
                        float* __restrict__ gxT2, const float* __restrict__ Whh,
                        const float* __restrict__ bhh, const float* __restrict__ W1,
                        const float* __restrict__ b1, const float* __restrict__ lng,
                        const float* __restrict__ lnb, const float* __restrict__ W2,
                        const float* __restrict__ b2v, float* __restrict__ out,
                        int N, int E, int nch, int naccum, int hist) {
    int t = threadIdx.x;
    int bid = blockIdx.x;

    if (bid >= 9 && bid < 9 + NGX) {
        // ================= gx block: gx FIRST, then count slice =================
        int idx = bid - 9;
        __shared__ float xs[H];
        int tt = idx >> 1, bb = idx & 1;
        if (t < H) xs[t] = x[(bb * TT + tt) * H + t];
        __syncthreads();
        for (int o = t; o < 384; o += 256) {
            const float4* wp = (const float4*)(Wih + o * H);
            float acc = 0.f;
#pragma unroll
            for (int i = 0; i < 32; ++i) {
                float4 w = wp[i];
                acc += w.x * xs[4 * i] + w.y * xs[4 * i + 1] + w.z * xs[4 * i + 2] +
                       w.w * xs[4 * i + 3];
            }
            float bias = bih[o] + (o < TWO_H ? bhh[o] : 0.f);  // bhh_n not foldable
            int g = o >> 7, j = o & 127;
            gxT2[((size_t)(tt * 128 + j) * 2 + bb) * 4 + g] = acc + bias;
        }
        __syncthreads();
        if (t == 0) {
            __threadfence();
            atomicAdd(&flags[8 + (idx >> 4)], 1);  // chunk-group ready
        }
        if (hist) {
            int per = (E + NGX - 1) / NGX;
            int e0 = idx * per, e1 = min(E, e0 + per);
            for (int e = e0 + t; e < e1; e += 256) {
                int r = rel[e];
                atomicAdd(&csd[(size_t)src[e] * 8 + r], 1u);
                atomicAdd(&csd[(size_t)dst[e] * 8 + r], 65536u);
            }
            __syncthreads();
            if (t == 0) {
                __threadfence();
                atomicAdd(&flags[2], 1);
            }
        }
        return;
    }

    if (bid >= 9 + NGX) {
        // ================= accum: stream nodes once, weighted by counts =================
        int ai = bid - 9 - NGX;
        if (t == 0) {
            while (atomicAdd(&flags[2], 0) < NGX) __builtin_amdgcn_s_sleep(8);
            __threadfence();
        }
        __syncthreads();
        int n0 = ai * nch, n1 = min(N, n0 + nch);
        float sA[8] = {0, 0, 0, 0, 0, 0, 0, 0};
        float sB[8] = {0, 0, 0, 0, 0, 0, 0, 0};
        float caR[8] = {0, 0, 0, 0, 0, 0, 0, 0};
        int n = n0;
        for (; n + 4 <= n1; n += 4) {
            float v0 = nodes[(size_t)(n + 0) * 256 + t];
            float v1 = nodes[(size_t)(n + 1) * 256 + t];
            float v2 = nodes[(size_t)(n + 2) * 256 + t];
            float v3 = nodes[(size_t)(n + 3) * 256 + t];
            uint4 a0 = *(const uint4*)(csd + (size_t)(n + 0) * 8);
            uint4 a1 = *(const uint4*)(csd + (size_t)(n + 0) * 8 + 4);
            uint4 b0 = *(const uint4*)(csd + (size_t)(n + 1) * 8);
            uint4 b1u = *(const uint4*)(csd + (size_t)(n + 1) * 8 + 4);
            uint4 c0 = *(const uint4*)(csd + (size_t)(n + 2) * 8);
            uint4 c1 = *(const uint4*)(csd + (size_t)(n + 2) * 8 + 4);
            uint4 d0 = *(const uint4*)(csd + (size_t)(n + 3) * 8);
            uint4 d1 = *(const uint4*)(csd + (size_t)(n + 3) * 8 + 4);
            uint ca[8] = {a0.x, a0.y, a0.z, a0.w, a1.x, a1.y, a1.z, a1.w};
            uint cb[8] = {b0.x, b0.y, b0.z, b0.w, b1u.x, b1u.y, b1u.z, b1u.w};
            uint cc[8] = {c0.x, c0.y, c0.z, c0.w, c1.x, c1.y, c1.z, c1.w};
            uint cd2[8] = {d0.x, d0.y, d0.z, d0.w, d1.x, d1.y, d1.z, d1.w};
#pragma unroll
            for (int r = 0; r < 8; ++r) {
                float fs0 = (float)(ca[r] & 0xffffu), fd0 = (float)(ca[r] >> 16);
                float fs1 = (float)(cb[r] & 0xffffu), fd1 = (float)(cb[r] >> 16);
                float fs2 = (float)(cc[r] & 0xffffu), fd2 = (float)(cc[r] >> 16);
                float fs3 = (float)(cd2[r] & 0xffffu), fd3 = (float)(cd2[r] >> 16);
                sA[r] += fs0 * v0 + fs1 * v1 + fs2 * v2 + fs3 * v3;
                sB[r] += fd0 * v0 + fd1 * v1 + fd2 * v2 + fd3 * v3;
                caR[r] += fs0 + fs1 + fs2 + fs3;
            }
        }
        for (; n < n1; ++n) {
            float v = nodes[(size_t)n * 256 + t];
            const uint* cp = csd + (size_t)n * 8;
            uint4 c0 = *(const uint4*)cp;
            uint4 c1 = *(const uint4*)(cp + 4);
            uint cc[8] = {c0.x, c0.y, c0.z, c0.w, c1.x, c1.y, c1.z, c1.w};
#pragma unroll
            for (int r = 0; r < 8; ++r) {
                float fs = (float)(cc[r] & 0xffffu);
                float fd = (float)(cc[r] >> 16);
                sA[r] += fs * v;
                sB[r] += fd * v;
                caR[r] += fs;
            }
        }
        int b = t >> 7, h = t & 127;
#pragma unroll
        for (int r = 0; r < 8; ++r) {
            atomicAdd(&Sg[r * 512 + b * 256 + h], sA[r]);
            atomicAdd(&Sg[r * 512 + b * 256 + 128 + h], sB[r]);
        }
        if (t == 0) {
#pragma unroll
            for (int r = 0; r < 8; ++r) atomicAdd(&cntg[r], caR[r]);
        }
        __syncthreads();
        if (t == 0) {
            __threadfence();
            atomicAdd(&flags[0], 1);
        }
        return;
    }

    if (bid >= 1) {
        // ================= combine r: gs += (S_r @ W_r + cnt_r*b_r)/E =================
        int r = bid - 1;
        __shared__ float Sc[512];
        if (t == 0) {
            while (atomicAdd(&flags[0], 0) < naccum) __builtin_amdgcn_s_sleep(8);
        }
        __syncthreads();
        for (int i = t; i < 512; i += 256) Sc[i] = atomicAdd(&Sg[r * 512 + i], 0.f);
        __syncthreads();
        int b = t >> 7, h = t & 127;
        const float* Wr = relW + (size_t)r * TWO_H * H;
        float acc = 0.f;
#pragma unroll 8
        for (int c = 0; c < TWO_H; ++c) acc += Sc[b * 256 + c] * Wr[c * H + h];
        acc += atomicAdd(&cntg[r], 0.f) * relb[r * H + h];
        atomicAdd(&gs[t], acc * invE);
        __syncthreads();
        if (t == 0) {
            __threadfence();
            atomicAdd(&flags[1], 1);
        }
        return;
    }

    // ================= block 0: GRU, 4 waves, LDS-staged gx =================
    __shared__ __align__(16) unsigned short h2[2][5][144];
    __shared__ __align__(16) float gxs[2][8][256][4];  // 2 x 32KB staged gx chunks
    __shared__ float hfl[256];
    __shared__ float gl2[2][H];
    __shared__ float yl[2][TWO_H];
    __shared__ float red[16];

    int w = t >> 6, l = t & 63;

    for (int i = t; i < 2 * 5 * 144; i += 256) ((unsigned short*)h2)[i] = 0;

    // B fragments: wave w owns j in [32w,32w+32): tiles ti=(g=ti>>1, jh=ti&1)
    short8 Bf[6][4];
#pragma unroll
    for (int ti = 0; ti < 6; ++ti) {
        int row = ((ti >> 1) * 8 + 2 * w + (ti & 1)) * 16 + (l & 15);
#pragma unroll
        for (int kt = 0; kt < 4; ++kt) {
            const float4* wp = (const float4*)(Whh + row * H + kt * 32 + (l >> 4) * 8);
            float4 w0 = wp[0], w1 = wp[1];
            float ww[8] = {w0.x, w0.y, w0.z, w0.w, w1.x, w1.y, w1.z, w1.w};
            short8 v8;
#pragma unroll
            for (int e = 0; e < 8; ++e) v8[e] = (short)bf_rne(ww[e]);
            Bf[ti][kt] = v8;
        }
    }

    int al = l & 15;
    int rr = al < 4 ? al : 4;  // A-row; rows >=4 read the zero row (broadcast)
    int kg = (l >> 4) * 8;

    // gate lanes: l<16; 4 units each: (b, jh), j = w*32 + jh*16 + l
    float hpv[2][2] = {{0.f, 0.f}, {0.f, 0.f}};  // [jh][b]
    float bhnv[2];
    int j0 = w * 32 + l;
    if (l < 16) {
        bhnv[0] = bhh[TWO_H + j0];
        bhnv[1] = bhh[TWO_H + j0 + 16];
    }

    // wait only for chunk-0's 16 gx producers, then stage chunk 0
    if (t == 0) {
        while (atomicAdd(&flags[8 + 0], 0) < 16) __builtin_amdgcn_s_sleep(2);
        __threadfence();
    }
    __syncthreads();

    {
        float* lb = &gxs[0][0][0][0];
#pragma unroll
        for (int i = 0; i < 8; ++i) {
            __builtin_amdgcn_global_load_lds(
                (const __attribute__((address_space(1))) uint*)(gxT2 + w * 2048 + i * 256 + l * 4),
                (__attribute__((address_space(3))) uint*)(lb + w * 2048 + i * 256),
                16, 0, 0);
        }
    }
    __syncthreads();  // drains vmcnt(0): chunk 0 staged; h2 zeros visible

    __builtin_amdgcn_s_setprio(1);
    for (int c = 0; c < 8; ++c) {
        if (c < 7) {
            // wait for chunk c+1 producers, then issue its staging (8 steps of slack)
            if (t == 0) {
                while (atomicAdd(&flags[8 + c + 1], 0) < 16) __builtin_amdgcn_s_sleep(2);
                __threadfence();
            }
            __builtin_amdgcn_s_barrier();
            float* lb = &gxs[(c + 1) & 1][0][0][0];
            const float* sb = gxT2 + (size_t)(c + 1) * 8192;
#pragma unroll
            for (int i = 0; i < 8; ++i) {
                __builtin_amdgcn_global_load_lds(
                    (const __attribute__((address_space(1))) uint*)(sb + w * 2048 + i * 256 + l * 4),
                    (__attribute__((address_space(3))) uint*)(lb + w * 2048 + i * 256),
                    16, 0, 0);
            }
        }
#pragma unroll
        for (int i = 0; i < 8; ++i) {
            int p = i & 1, q = p ^ 1;

            // hoisted gx read: its ds latency overlaps the MFMA phase
            float4 cgl[2][2];
            if (l < 16) {
#pragma unroll
                for (int jh = 0; jh < 2; ++jh)
#pragma unroll
                    for (int b = 0; b < 2; ++b)
                        cgl[jh][b] = *(const float4*)&gxs[c & 1][i][(j0 + jh * 16) * 2 + b][0];
            }

            short8 A[4];
#pragma unroll
            for (int kt = 0; kt < 4; ++kt)
                A[kt] = *(const short8*)&h2[p][rr][kt * 32 + kg];

            f32x4 acc[6];
#pragma unroll
            for (int ti = 0; ti < 6; ++ti) acc[ti] = (f32x4){0.f, 0.f, 0.f, 0.f};
#pragma unroll
            for (int kt = 0; kt < 4; ++kt) {
#pragma unroll
                for (int ti = 0; ti < 6; ++ti) acc[ti] = mfma_bf16(A[kt], Bf[ti][kt], acc[ti]);
            }

            if (l < 16) {
#pragma unroll
                for (int jh = 0; jh < 2; ++jh) {
#pragma unroll
                    for (int b = 0; b < 2; ++b) {
                        const float4 cg = cgl[jh][b];
                        float ghr = acc[0 * 2 + jh][b] + acc[0 * 2 + jh][2 + b];
                        float ghz = acc[1 * 2 + jh][b] + acc[1 * 2 + jh][2 + b];
                        float ghn = acc[2 * 2 + jh][b] + acc[2 * 2 + jh][2 + b];
                        float rg = sigf(cg.x + ghr);
                        float zg = sigf(cg.y + ghz);
                        float nn = cg.z + rg * (ghn + bhnv[jh]);
                        float th = 2.f * sigf(2.f * nn) - 1.f;
                        float hn2 = (1.f - zg) * th + zg * hpv[jh][b];
                        hpv[jh][b] = hn2;
                        unsigned short hh, ll;
                        split_rne(hn2, hh, ll);
                        int j = j0 + jh * 16;
                        h2[q][b][j] = hh;
                        h2[q][2 + b][j] = ll;
                    }
                }
            }
            __builtin_amdgcn_sched_barrier(0);
            if (i == 7) {
                asm volatile("s_waitcnt vmcnt(0) lgkmcnt(0)" ::: "memory");
            } else {
                asm volatile("s_waitcnt lgkmcnt(0)" ::: "memory");
            }
            __builtin_amdgcn_s_barrier();
            __builtin_amdgcn_sched_barrier(0);
        }
    }
    __builtin_amdgcn_s_setprio(0);

    // ---- tail: wait combine, then MLP + LN ----
    if (l < 16) {
#pragma unroll
        for (int jh = 0; jh < 2; ++jh)
#pragma unroll
            for (int b = 0; b < 2; ++b) hfl[b * 128 + j0 + jh * 16] = hpv[jh][b];
    }
    if (t == 0) {
        while (atomicAdd(&flags[1], 0) < 8) __builtin_amdgcn_s_sleep(8);
    }
    __syncthreads();
    gl2[t >> 7][t & 127] = atomicAdd(&gs[t], 0.f) + hfl[t];
    __syncthreads();

    float h1_0 = b1[t], h1_1 = b1[t];
    for (int i = 0; i < H; ++i) {
        float wv = W1[i * TWO_H + t];
        h1_0 += gl2[0][i] * wv;
        h1_1 += gl2[1][i] * wv;
    }
    float s10 = h1_0, s20 = h1_0 * h1_0, s11 = h1_1, s21 = h1_1 * h1_1;
#pragma unroll
    for (int off = 32; off; off >>= 1) {
        s10 += __shfl_xor(s10, off);
        s20 += __shfl_xor(s20, off);
        s11 += __shfl_xor(s11, off);
        s21 += __shfl_xor(s21, off);
    }
    if (l == 0) {
        red[w * 4 + 0] = s10; red[w * 4 + 1] = s20;
        red[w * 4 + 2] = s11; red[w * 4 + 3] = s21;
    }
    __syncthreads();
    {
        float S10 = red[0] + red[4] + red[8] + red[12];
        float S20 = red[1] + red[5] + red[9] + red[13];
        float S11 = red[2] + red[6] + red[10] + red[14];
        float S21 = red[3] + red[7] + red[11] + red[15];
        float mu0 = S10 / 256.f, mu1 = S11 / 256.f;
        float v0 = S20 / 256.f - mu0 * mu0, v1 = S21 / 256.f - mu1 * mu1;
        float is0 = rsqrtf(v0 + 1e-5f), is1 = rsqrtf(v1 + 1e-5f);
        float y0 = (h1_0 - mu0) * is0 * lng[t] + lnb[t];
        float y1 = (h1_1 - mu1) * is1 * lng[t] + lnb[t];
        yl[0][t] = fmaxf(y0, 0.f);
        yl[1][t] = fmaxf(y1, 0.f);
    }
    __syncthreads();
    if (t < H) {
        float a0 = b2v[t], a1 = b2v[t];
        for (int i = 0; i < TWO_H; ++i) {
            float wv = W2[i * H + t];
            a0 += yl[0][i] * wv;
            a1 += yl[1][i] * wv;
        }
        out[t] = a0;
        out[H + t] = a1;
    }
}

extern "C" void kernel_launch(void* const* d_in, const int* in_sizes, int n_in,
                              void* d_out, int out_size, void* d_ws, size_t ws_size,
                              hipStream_t stream) {
    const float* nodes = (const float*)d_in[0];
    const float* temporal = (const float*)d_in[1];
    const float* relW = (const float*)d_in[2];
    const float* relb = (const float*)d_in[3];
    const float* gru_Wih = (const float*)d_in[4];
    const float* gru_Whh = (const float*)d_in[5];
    const float* gru_bih = (const float*)d_in[6];
    const float* gru_bhh = (const float*)d_in[7];
    const float* mlp_W1 = (const float*)d_in[8];
    const float* mlp_b1 = (const float*)d_in[9];
    const float* ln_g = (const float*)d_in[10];
    const float* ln_b = (const float*)d_in[11];
    const float* mlp_W2 = (const float*)d_in[12];
    const float* mlp_b2 = (const float*)d_in[13];
    const int* src = (const int*)d_in[14];
    const int* rel = (const int*)d_in[15];
    const int* dst = (const int*)d_in[16];
    float* out = (float*)d_out;

    int E = in_sizes[14];
    int N = in_sizes[0] / 256;

    // ws layout (float units): gs(256) | cntg(8) | flags(24 ints) | Sg(4096) | csd | gxT2
    float* ws = (float*)d_ws;
    float* gs = ws;                     // 0..255
    float* cntg = ws + 256;             // 256..263
    int* flags = (int*)(ws + 264);      // 264..287 (24 ints)
    float* Sg = ws + 288;               // 288..4383
    uint* csd = (uint*)(ws + 4384);     // 8*N (hist only)

    size_t need_hist = (size_t)(4384 + 8 * N + 65536) * 4;
    int hist = ws_size >= need_hist ? 1 : 0;

    float* gxT2 = hist ? (ws + 4384 + 8 * N) : (ws + 4384);
    size_t zbytes = hist ? (size_t)(4384 + 8 * N) * 4 : (size_t)4384 * 4;
    hipMemsetAsync(d_ws, 0, zbytes, stream);

    int naccum, nblk;
    if (hist) {
        naccum = NACC;
        nblk = 9 + NGX + NACC;
    } else {
        int epb = (E + 511) / 512;
        k_edges_fb<<<512, 256, 0, stream>>>(nodes, src, rel, dst, Sg, cntg, E, epb);
        naccum = 0;
        nblk = 9 + NGX;
    }
    int nch = (N + NACC - 1) / NACC;

    k_fused<<<nblk, 256, 0, stream>>>(nodes, src, rel, dst, temporal, gru_Wih, gru_bih,
                                      csd, Sg, cntg, relW, relb, gs, flags,
                                      1.f / (float)E, gxT2, gru_Whh, gru_bhh, mlp_W1,
                                      mlp_b1, ln_g, ln_b, mlp_W2, mlp_b2, out,
                                      N, E, nch, naccum, hist);
}

// Round 12
// 86.220 us; speedup vs baseline: 1.4401x; 1.3348x over previous
//
#include <hip/hip_runtime.h>
#include <hip/hip_bf16.h>
#include <math.h>

#define H 128
#define TT 64
#define TWO_H 256
#define NGX 128
#define NACC 128

typedef short short8 __attribute__((ext_vector_type(8)));
typedef __bf16 bf16x8_t __attribute__((ext_vector_type(8)));
typedef float f32x4 __attribute__((ext_vector_type(4)));
typedef unsigned int uint;

__device__ inline unsigned short bf_rne(float f) {
    __hip_bfloat16 b = __float2bfloat16(f);
    return __builtin_bit_cast(unsigned short, b);
}
__device__ inline void split_rne(float f, unsigned short& hi, unsigned short& lo) {
    __hip_bfloat16 h1 = __float2bfloat16(f);
    float fh = __bfloat162float(h1);
    hi = __builtin_bit_cast(unsigned short, h1);
    lo = bf_rne(f - fh);
}
__device__ inline f32x4 mfma_bf16(short8 a, short8 b, f32x4 c) {
    return __builtin_amdgcn_mfma_f32_16x16x32_bf16(
        __builtin_bit_cast(bf16x8_t, a), __builtin_bit_cast(bf16x8_t, b), c, 0, 0, 0);
}
__device__ inline float sigf(float x) { return 1.f / (1.f + __expf(-x)); }

// ---------- fallback (only if workspace too small for histogram path) ----------
__global__ void k_edges_fb(const float* __restrict__ nodes, const int* __restrict__ src,
                           const int* __restrict__ rel, const int* __restrict__ dst,
                           float* __restrict__ Sg, float* __restrict__ cntg, int E, int epb) {
    __shared__ float Sl[8 * 512];
    __shared__ float cnt[8];
    int t = threadIdx.x;
    for (int i = t; i < 8 * 512; i += 256) Sl[i] = 0.f;
    if (t < 8) cnt[t] = 0.f;
    __syncthreads();
    int e0 = blockIdx.x * epb, e1 = min(E, e0 + epb);
    int tS = ((t >> 7) << 8) + (t & 127);
    for (int e = e0; e < e1; ++e) {
        int r = rel[e];
        float vs = nodes[(size_t)src[e] * 256 + t];
        float vd = nodes[(size_t)dst[e] * 256 + t];
        Sl[r * 512 + tS] += vs;
        Sl[r * 512 + tS + 128] += vd;
        if (t == 0) cnt[r] += 1.f;
    }
    __syncthreads();
    for (int i = t; i < 8 * 512; i += 256) atomicAdd(&Sg[i], Sl[i]);
    if (t < 8) atomicAdd(&cntg[t], cnt[t]);
}

// ===== single fused kernel: GRU(b0)|GRU(b1) | combine | gx(+count) | accum =====
// flags: [0]=accum done, [1]=combine done, [2]=count done, [5]=gx done
__launch_bounds__(256, 1)
__global__ void k_fused(const float* __restrict__ nodes, const int* __restrict__ src,
                        const int* __restrict__ rel, const int* __restrict__ dst,
                        const float* __restrict__ x, const float* __restrict__ Wih,
                        const float* __restrict__ bih, uint* __restrict__ csd,
                        float* __restrict__ Sg, float* __restrict__ cntg,
                        const float* __restrict__ relW, const float* __restrict__ relb,
                        float* __restrict__ gs, int* __restrict__ flags, float invE,
                        float* __restrict__ gxT2, const float* __restrict__ Whh,
                        const float* __restrict__ bhh, const float* __restrict__ W1,
                        const float* __restrict__ b1, const float* __restrict__ lng,
                        const float* __restrict__ lnb, const float* __restrict__ W2,
                        const float* __restrict__ b2v, float* __restrict__ out,
                        int N, int E, int nch, int naccum, int hist) {
    int t = threadIdx.x;
    int bid = blockIdx.x;

    if (bid >= 10 && bid < 10 + NGX) {
        // ================= gx block: gx FIRST (signal), then count slice =================
        int idx = bid - 10;
        __shared__ float xs[H];
        int tt = idx >> 1, bb = idx & 1;
        if (t < H) xs[t] = x[(bb * TT + tt) * H + t];
        __syncthreads();
        for (int o = t; o < 384; o += 256) {
            const float4* wp = (const float4*)(Wih + o * H);
            float acc = 0.f;
#pragma unroll
            for (int i = 0; i < 32; ++i) {
                float4 w = wp[i];
                acc += w.x * xs[4 * i] + w.y * xs[4 * i + 1] + w.z * xs[4 * i + 2] +
                       w.w * xs[4 * i + 3];
            }
            float bias = bih[o] + (o < TWO_H ? bhh[o] : 0.f);  // bhh_n not foldable
            int g = o >> 7, j = o & 127;
            // layout [b][t][j][4]
            gxT2[((size_t)(bb * TT + tt) * 128 + j) * 4 + g] = acc + bias;
        }
        __syncthreads();
        if (t == 0) {
            __threadfence();
            atomicAdd(&flags[5], 1);  // gx ready
        }
        if (hist) {
            int per = (E + NGX - 1) / NGX;
            int e0 = idx * per, e1 = min(E, e0 + per);
            for (int e = e0 + t; e < e1; e += 256) {
                int r = rel[e];
                atomicAdd(&csd[(size_t)src[e] * 8 + r], 1u);
                atomicAdd(&csd[(size_t)dst[e] * 8 + r], 65536u);
            }
            __syncthreads();
            if (t == 0) {
                __threadfence();
                atomicAdd(&flags[2], 1);
            }
        }
        return;
    }

    if (bid >= 10 + NGX) {
        // ================= accum: stream nodes once, weighted by counts =================
        int ai = bid - 10 - NGX;
        if (t == 0) {
            while (atomicAdd(&flags[2], 0) < NGX) __builtin_amdgcn_s_sleep(8);
            __threadfence();
        }
        __syncthreads();
        int n0 = ai * nch, n1 = min(N, n0 + nch);
        float sA[8] = {0, 0, 0, 0, 0, 0, 0, 0};
        float sB[8] = {0, 0, 0, 0, 0, 0, 0, 0};
        float caR[8] = {0, 0, 0, 0, 0, 0, 0, 0};
        int n = n0;
        for (; n + 4 <= n1; n += 4) {
            float v0 = nodes[(size_t)(n + 0) * 256 + t];
            float v1 = nodes[(size_t)(n + 1) * 256 + t];
            float v2 = nodes[(size_t)(n + 2) * 256 + t];
            float v3 = nodes[(size_t)(n + 3) * 256 + t];
            uint4 a0 = *(const uint4*)(csd + (size_t)(n + 0) * 8);
            uint4 a1 = *(const uint4*)(csd + (size_t)(n + 0) * 8 + 4);
            uint4 b0 = *(const uint4*)(csd + (size_t)(n + 1) * 8);
            uint4 b1u = *(const uint4*)(csd + (size_t)(n + 1) * 8 + 4);
            uint4 c0 = *(const uint4*)(csd + (size_t)(n + 2) * 8);
            uint4 c1 = *(const uint4*)(csd + (size_t)(n + 2) * 8 + 4);
            uint4 d0 = *(const uint4*)(csd + (size_t)(n + 3) * 8);
            uint4 d1 = *(const uint4*)(csd + (size_t)(n + 3) * 8 + 4);
            uint ca[8] = {a0.x, a0.y, a0.z, a0.w, a1.x, a1.y, a1.z, a1.w};
            uint cb[8] = {b0.x, b0.y, b0.z, b0.w, b1u.x, b1u.y, b1u.z, b1u.w};
            uint cc[8] = {c0.x, c0.y, c0.z, c0.w, c1.x, c1.y, c1.z, c1.w};
            uint cd2[8] = {d0.x, d0.y, d0.z, d0.w, d1.x, d1.y, d1.z, d1.w};
#pragma unroll
            for (int r = 0; r < 8; ++r) {
                float fs0 = (float)(ca[r] & 0xffffu), fd0 = (float)(ca[r] >> 16);
                float fs1 = (float)(cb[r] & 0xffffu), fd1 = (float)(cb[r] >> 16);
                float fs2 = (float)(cc[r] & 0xffffu), fd2 = (float)(cc[r] >> 16);
                float fs3 = (float)(cd2[r] & 0xffffu), fd3 = (float)(cd2[r] >> 16);
                sA[r] += fs0 * v0 + fs1 * v1 + fs2 * v2 + fs3 * v3;
                sB[r] += fd0 * v0 + fd1 * v1 + fd2 * v2 + fd3 * v3;
                caR[r] += fs0 + fs1 + fs2 + fs3;
            }
        }
        for (; n < n1; ++n) {
            float v = nodes[(size_t)n * 256 + t];
            const uint* cp = csd + (size_t)n * 8;
            uint4 c0 = *(const uint4*)cp;
            uint4 c1 = *(const uint4*)(cp + 4);
            uint cc[8] = {c0.x, c0.y, c0.z, c0.w, c1.x, c1.y, c1.z, c1.w};
#pragma unroll
            for (int r = 0; r < 8; ++r) {
                float fs = (float)(cc[r] & 0xffffu);
                float fd = (float)(cc[r] >> 16);
                sA[r] += fs * v;
                sB[r] += fd * v;
                caR[r] += fs;
            }
        }
        int b = t >> 7, h = t & 127;
#pragma unroll
        for (int r = 0; r < 8; ++r) {
            atomicAdd(&Sg[r * 512 + b * 256 + h], sA[r]);
            atomicAdd(&Sg[r * 512 + b * 256 + 128 + h], sB[r]);
        }
        if (t == 0) {
#pragma unroll
            for (int r = 0; r < 8; ++r) atomicAdd(&cntg[r], caR[r]);
        }
        __syncthreads();
        if (t == 0) {
            __threadfence();
            atomicAdd(&flags[0], 1);
        }
        return;
    }

    if (bid >= 2) {
        // ================= combine r: gs += (S_r @ W_r + cnt_r*b_r)/E =================
        int r = bid - 2;
        __shared__ float Sc[512];
        if (t == 0) {
            while (atomicAdd(&flags[0], 0) < naccum) __builtin_amdgcn_s_sleep(8);
        }
        __syncthreads();
        for (int i = t; i < 512; i += 256) Sc[i] = atomicAdd(&Sg[r * 512 + i], 0.f);
        __syncthreads();
        int b = t >> 7, h = t & 127;
        const float* Wr = relW + (size_t)r * TWO_H * H;
        float acc = 0.f;
#pragma unroll 8
        for (int c = 0; c < TWO_H; ++c) acc += Sc[b * 256 + c] * Wr[c * H + h];
        acc += atomicAdd(&cntg[r], 0.f) * relb[r * H + h];
        atomicAdd(&gs[t], acc * invE);
        __syncthreads();
        if (t == 0) {
            __threadfence();
            atomicAdd(&flags[1], 1);
        }
        return;
    }

    // ============ blocks 0,1: per-batch GRU, 4 waves, LDS-staged gx ============
    int b = bid;  // batch index
    // h rows: 0=hi 1=lo 2=zero; double-buffered; pad 144 -> max 2-way bank alias (free)
    __shared__ __align__(16) unsigned short h2[2][3][144];
    __shared__ __align__(16) float gxs[2][8][128][4];  // 2 x 16KB staged gx chunks
    __shared__ float hfl[H];
    __shared__ float gl2[H];
    __shared__ float yl[TWO_H];
    __shared__ float red[8];

    int w = t >> 6, l = t & 63;

    for (int i = t; i < 2 * 3 * 144; i += 256) ((unsigned short*)h2)[i] = 0;

    // B fragments: wave w owns gates r,z,n for j in [32w,32w+32): 6 tiles (g, jh)
    short8 Bf[6][4];
#pragma unroll
    for (int ti = 0; ti < 6; ++ti) {
        int row = ((ti >> 1) * 8 + 2 * w + (ti & 1)) * 16 + (l & 15);
#pragma unroll
        for (int kt = 0; kt < 4; ++kt) {
            const float4* wp = (const float4*)(Whh + row * H + kt * 32 + (l >> 4) * 8);
            float4 w0 = wp[0], w1 = wp[1];
            float ww[8] = {w0.x, w0.y, w0.z, w0.w, w1.x, w1.y, w1.z, w1.w};
            short8 v8;
#pragma unroll
            for (int e = 0; e < 8; ++e) v8[e] = (short)bf_rne(ww[e]);
            Bf[ti][kt] = v8;
        }
    }

    int al = l & 15;
    int rr = al < 2 ? al : 2;  // A-row: 0=hi 1=lo, >=2 zero broadcast
    int kg = (l >> 4) * 8;

    // gate lanes l<16: 2 units (jh), j = w*32 + jh*16 + l
    float hpv[2] = {0.f, 0.f};
    float bhnv[2];
    int j0 = w * 32 + l;
    if (l < 16) {
        bhnv[0] = bhh[TWO_H + j0];
        bhnv[1] = bhh[TWO_H + j0 + 16];
    }

    const float* gxb = gxT2 + (size_t)b * TT * 512;  // this batch's gx [64][128][4]

    // wait once for ALL gx producers, then stage chunk 0 (16KB)
    if (t == 0) {
        while (atomicAdd(&flags[5], 0) < NGX) __builtin_amdgcn_s_sleep(2);
        __threadfence();
    }
    __syncthreads();
    {
        float* lb = &gxs[0][0][0][0];
#pragma unroll
        for (int i = 0; i < 4; ++i) {
            __builtin_amdgcn_global_load_lds(
                (const __attribute__((address_space(1))) uint*)(gxb + w * 1024 + i * 256 + l * 4),
                (__attribute__((address_space(3))) uint*)(lb + w * 1024 + i * 256),
                16, 0, 0);
        }
    }
    __syncthreads();  // drains vmcnt(0): chunk 0 staged; h2 zeros visible

    __builtin_amdgcn_s_setprio(1);
    for (int c = 0; c < 8; ++c) {
        if (c < 7) {
            float* lb = &gxs[(c + 1) & 1][0][0][0];
            const float* sb = gxb + (size_t)(c + 1) * 4096;
#pragma unroll
            for (int i = 0; i < 4; ++i) {
                __builtin_amdgcn_global_load_lds(
                    (const __attribute__((address_space(1))) uint*)(sb + w * 1024 + i * 256 + l * 4),
                    (__attribute__((address_space(3))) uint*)(lb + w * 1024 + i * 256),
                    16, 0, 0);
            }
        }
#pragma unroll
        for (int i = 0; i < 8; ++i) {
            int p = i & 1, q = p ^ 1;

            short8 A[4];
#pragma unroll
            for (int kt = 0; kt < 4; ++kt)
                A[kt] = *(const short8*)&h2[p][rr][kt * 32 + kg];

            f32x4 acc[6];
#pragma unroll
            for (int ti = 0; ti < 6; ++ti) acc[ti] = (f32x4){0.f, 0.f, 0.f, 0.f};
#pragma unroll
            for (int kt = 0; kt < 4; ++kt) {
#pragma unroll
                for (int ti = 0; ti < 6; ++ti) acc[ti] = mfma_bf16(A[kt], Bf[ti][kt], acc[ti]);
            }

            if (l < 16) {
#pragma unroll
                for (int jh = 0; jh < 2; ++jh) {
                    int j = j0 + jh * 16;
                    const float4 cg = *(const float4*)&gxs[c & 1][i][j][0];
                    float ghr = acc[0 + jh][0] + acc[0 + jh][1];  // hi + lo rows
                    float ghz = acc[2 + jh][0] + acc[2 + jh][1];
                    float ghn = acc[4 + jh][0] + acc[4 + jh][1];
                    float rg = sigf(cg.x + ghr);
                    float zg = sigf(cg.y + ghz);
                    float nn = cg.z + rg * (ghn + bhnv[jh]);
                    float th = 2.f * sigf(2.f * nn) - 1.f;
                    float hn2 = (1.f - zg) * th + zg * hpv[jh];
                    hpv[jh] = hn2;
                    unsigned short hh, ll;
                    split_rne(hn2, hh, ll);
                    h2[q][0][j] = hh;
                    h2[q][1][j] = ll;
                }
            }
            __builtin_amdgcn_sched_barrier(0);
            if (i == 7) {
                asm volatile("s_waitcnt vmcnt(0) lgkmcnt(0)" ::: "memory");
            } else {
                asm volatile("s_waitcnt lgkmcnt(0)" ::: "memory");
            }
            __builtin_amdgcn_s_barrier();
            __builtin_amdgcn_sched_barrier(0);
        }
    }
    __builtin_amdgcn_s_setprio(0);

    // ---- per-batch tail: wait combine, then MLP + LN ----
    if (l < 16) {
        hfl[j0] = hpv[0];
        hfl[j0 + 16] = hpv[1];
    }
    if (t == 0) {
        while (atomicAdd(&flags[1], 0) < 8) __builtin_amdgcn_s_sleep(8);
    }
    __syncthreads();
    if (t < H) gl2[t] = atomicAdd(&gs[b * H + t], 0.f) + hfl[t];
    __syncthreads();

    float h1 = b1[t];
    for (int i = 0; i < H; ++i) h1 += gl2[i] * W1[i * TWO_H + t];
    float s1 = h1, s2 = h1 * h1;
#pragma unroll
    for (int off = 32; off; off >>= 1) {
        s1 += __shfl_xor(s1, off);
        s2 += __shfl_xor(s2, off);
    }
    if (l == 0) {
        red[w * 2] = s1;
        red[w * 2 + 1] = s2;
    }
    __syncthreads();
    {
        float S1 = red[0] + red[2] + red[4] + red[6];
        float S2 = red[1] + red[3] + red[5] + red[7];
        float mu = S1 / 256.f;
        float var = S2 / 256.f - mu * mu;
        float is = rsqrtf(var + 1e-5f);
        float y = (h1 - mu) * is * lng[t] + lnb[t];
        yl[t] = fmaxf(y, 0.f);
    }
    __syncthreads();
    if (t < H) {
        float a = b2v[t];
        for (int i = 0; i < TWO_H; ++i) a += yl[i] * W2[i * H + t];
        out[b * H + t] = a;
    }
}

extern "C" void kernel_launch(void* const* d_in, const int* in_sizes, int n_in,
                              void* d_out, int out_size, void* d_ws, size_t ws_size,
                              hipStream_t stream) {
    const float* nodes = (const float*)d_in[0];
    const float* temporal = (const float*)d_in[1];
    const float* relW = (const float*)d_in[2];
    const float* relb = (const float*)d_in[3];
    const float* gru_Wih = (const float*)d_in[4];
    const float* gru_Whh = (const float*)d_in[5];
    const float* gru_bih = (const float*)d_in[6];
    const float* gru_bhh = (const float*)d_in[7];
    const float* mlp_W1 = (const float*)d_in[8];
    const float* mlp_b1 = (const float*)d_in[9];
    const float* ln_g = (const float*)d_in[10];
    const float* ln_b = (const float*)d_in[11];
    const float* mlp_W2 = (const float*)d_in[12];
    const float* mlp_b2 = (const float*)d_in[13];
    const int* src = (const int*)d_in[14];
    const int* rel = (const int*)d_in[15];
    const int* dst = (const int*)d_in[16];
    float* out = (float*)d_out;

    int E = in_sizes[14];
    int N = in_sizes[0] / 256;

    // ws layout (float units): gs(256) | cntg(8) | flags(24 ints) | Sg(4096) | csd | gxT2
    float* ws = (float*)d_ws;
    float* gs = ws;                     // 0..255
    float* cntg = ws + 256;             // 256..263
    int* flags = (int*)(ws + 264);      // 264..287
    float* Sg = ws + 288;               // 288..4383
    uint* csd = (uint*)(ws + 4384);     // 8*N (hist only)

    size_t need_hist = (size_t)(4384 + 8 * N + 65536) * 4;
    int hist = ws_size >= need_hist ? 1 : 0;

    float* gxT2 = hist ? (ws + 4384 + 8 * N) : (ws + 4384);
    size_t zbytes = hist ? (size_t)(4384 + 8 * N) * 4 : (size_t)4384 * 4;
    hipMemsetAsync(d_ws, 0, zbytes, stream);

    int naccum, nblk;
    if (hist) {
        naccum = NACC;
        nblk = 10 + NGX + NACC;
    } else {
        int epb = (E + 511) / 512;
        k_edges_fb<<<512, 256, 0, stream>>>(nodes, src, rel, dst, Sg, cntg, E, epb);
        naccum = 0;
        nblk = 10 + NGX;
    }
    int nch = (N + NACC - 1) / NACC;

    k_fused<<<nblk, 256, 0, stream>>>(nodes, src, rel, dst, temporal, gru_Wih, gru_bih,
                                      csd, Sg, cntg, relW, relb, gs, flags,
                                      1.f / (float)E, gxT2, gru_Whh, gru_bhh, mlp_W1,
                                      mlp_b1, ln_g, ln_b, mlp_W2, mlp_b2, out,
                                      N, E, nch, naccum, hist);
}